// Round 10
// baseline (78.769 us; speedup 1.0000x reference)
//
#include <hip/hip_runtime.h>

#define Hd 128
#define Wd 128
#define Cd 64
#define COd 64
#define Bd 4
#define HWd (Hd*Wd)

typedef __attribute__((ext_vector_type(8))) short  short8;
typedef __attribute__((ext_vector_type(4))) float  f32x4;
typedef __attribute__((ext_vector_type(2))) float  f32x2;

// Static device scratch.
__device__ __align__(16) short g_wbf[COd*576];                   // bf16 W[co][k], k=t*64+c
__device__ __align__(16) short g_woffbf[16*576];                 // bf16 w_off padded to 16 rows
__device__ float4 g_offs[Bd*HWd];                                // (off0, off1, s1, s2)
__device__ __align__(16) unsigned short g_xt[(size_t)Bd*HWd*Cd]; // bf16 NHWC x

static __device__ __forceinline__ unsigned short f2bf(float v) {
    unsigned u = __float_as_uint(v);
    u += 0x7FFFu + ((u >> 16) & 1u);   // RNE
    return (unsigned short)(u >> 16);
}
static __device__ __forceinline__ f32x2 bf2(unsigned u) {
    return (f32x2){__uint_as_float(u << 16), __uint_as_float(u & 0xFFFF0000u)};
}
static __device__ __forceinline__ unsigned cvtpk(float lo, float hi) {
    unsigned r;
    asm("v_cvt_pk_bf16_f32 %0, %1, %2" : "=v"(r) : "v"(lo), "v"(hi));
    return r;
}

// Prep: [0,512) NHWC ; [512,656) W->bf16 ; [656,692) w_off padded bf16.
__global__ __launch_bounds__(256) void k_prep(const float* __restrict__ x,
                                              const float* __restrict__ weight,
                                              const float* __restrict__ w_off) {
    int bid = blockIdx.x;
    if (bid < 512) {
        int b = bid >> 7, y = bid & 127;
        int px = threadIdx.x & 127;
        int h  = threadIdx.x >> 7;
        const float* xb = x + (size_t)b*Cd*HWd + y*Wd + px;
        unsigned short* ob = g_xt + ((size_t)(b*HWd) + y*Wd + px)*Cd + h*32;
        #pragma unroll
        for (int oct = 0; oct < 4; ++oct) {
            unsigned pk[4];
            #pragma unroll
            for (int e = 0; e < 4; ++e) {
                float v0 = xb[(size_t)(h*32 + oct*8 + 2*e    )*HWd];
                float v1 = xb[(size_t)(h*32 + oct*8 + 2*e + 1)*HWd];
                pk[e] = (unsigned)f2bf(v0) | ((unsigned)f2bf(v1) << 16);
            }
            *(uint4*)(ob + oct*8) = make_uint4(pk[0], pk[1], pk[2], pk[3]);
        }
    } else if (bid < 656) {
        int g = (bid - 512)*256 + threadIdx.x;     // 64*576
        if (g < COd*576) {
            int co = g / 576, k = g % 576;
            int t = k >> 6, c = k & 63;            // k = t*64 + c
            g_wbf[g] = (short)f2bf(weight[(co*Cd + c)*9 + t]);
        }
    } else {
        int g = (bid - 656)*256 + threadIdx.x;     // 16*576 = 9216
        if (g < 16*576) {
            int row = g / 576, k = g % 576;
            int t = k >> 6, c = k & 63;
            g_woffbf[g] = (row < 4) ? (short)f2bf(w_off[(row*Cd + c)*9 + t]) : (short)0;
        }
    }
}

// Offsets conv as MFMA mini-GEMM (r9 form): 1024 blocks x 64 px.
__global__ __launch_bounds__(256) void k_offs(const float* __restrict__ b_off) {
    int orig = blockIdx.x;               // 1024, XCD-banded
    int xcd = orig & 7, slot = orig >> 3;          // 0..127
    int g = xcd*2 + (slot >> 6);
    int s = slot & 63;
    int b  = g >> 2;
    int i  = (g & 3)*32 + (s >> 1);
    int j0 = (s & 1) << 6;

    int w  = threadIdx.x >> 6;
    int l  = threadIdx.x & 63;
    int pc = l & 15, q = l >> 4;
    int j  = j0 + w*16 + pc;

    const unsigned short* xb = g_xt + (size_t)b*HWd*Cd;
    const short* arow = g_woffbf + pc*576 + q*8;

    f32x4 acc = {0.f, 0.f, 0.f, 0.f};
    #pragma unroll
    for (int t = 0; t < 9; ++t) {
        int yy = i + t/3 - 1, xx = j + t%3 - 1;
        bool ok = (yy >= 0) & (yy <= 127) & (xx >= 0) & (xx <= 127);
        const unsigned short* p = xb + (size_t)(yy*Wd + xx)*Cd + q*8;
        uint4 u0 = ok ? *(const uint4*)p        : make_uint4(0,0,0,0);
        uint4 u1 = ok ? *(const uint4*)(p + 32) : make_uint4(0,0,0,0);
        short8 b0 = *(short8*)&u0;
        short8 b1 = *(short8*)&u1;
        short8 a0 = *(const short8*)(arow + (2*t    )*32);
        short8 a1 = *(const short8*)(arow + (2*t + 1)*32);
        acc = __builtin_amdgcn_mfma_f32_16x16x32_bf16(a0, b0, acc, 0, 0, 0);
        acc = __builtin_amdgcn_mfma_f32_16x16x32_bf16(a1, b1, acc, 0, 0, 0);
    }
    if (q == 0) {   // lanes 0..15: D rows 0..3 for pixel pc
        float o0 = acc[0] + b_off[0];
        float o1 = acc[1] + b_off[1];
        float o2 = fmaxf(acc[2] + b_off[2], 0.f) + 1.f;
        float o3 = fmaxf(acc[3] + b_off[3], 0.f) + 1.f;
        g_offs[(b*Hd + i)*Wd + j] = make_float4(o0, o1, o2, o3);
    }
}

// 512-thread, stage-all, one-barrier deform: 2048 blocks x 32 px; 36.8 KB LDS.
__global__ __launch_bounds__(512) void k_deform(const float* __restrict__ bias,
                                                float* __restrict__ out) {
    __shared__ uint4 lds_b[18*2*64];     // [ks][nt][slot] = 36864 B
    int orig = blockIdx.x;               // 2048, XCD-banded (bijective)
    int xcd = orig & 7, sl = orig >> 3;
    int g = xcd*2 + (sl >> 7);
    int s = sl & 127;
    int b = g >> 2;
    int i = (g & 3)*32 + (s >> 2);
    int j0 = (s & 3) << 5;

    int tid = threadIdx.x;

    // ---- Phase A: thread = (tp = tid>>8 wave-uniform, pxl, oct) ----
    {
        int tp  = tid >> 8;              // waves 0-3: taps 0,2,4,6,8 ; waves 4-7: 1,3,5,7
        int oct = tid & 7;
        int pxl = (tid >> 3) & 31;
        int jA  = j0 + pxl;
        int nt  = pxl >> 4, pcA = pxl & 15;
        int qA  = oct & 3, par = oct >> 2;
        int slotA = (pcA ^ (qA << 1)) + (qA << 4);

        const unsigned short* xb = g_xt + (size_t)b*HWd*Cd;
        float4 o4 = g_offs[(b*Hd + i)*Wd + jA];
        float off0 = o4.x, off1 = o4.y, s1v = o4.z, s2v = o4.w;

        #pragma unroll 1
        for (int t = tp; t < 9; t += 2) {
            float ys = (float)(i - 1) + (float)(t/3 - 1)*s1v + off0;
            float xs = (float)(jA - 1) + (float)(t%3 - 1)*s2v + off1;
            float y0f = floorf(ys), x0f = floorf(xs);
            float wy = ys - y0f, wx = xs - x0f;
            float vy0 = (y0f >=  0.f && y0f <= 127.f) ? 1.f : 0.f;
            float vy1 = (y0f >= -1.f && y0f <= 126.f) ? 1.f : 0.f;
            float vx0 = (x0f >=  0.f && x0f <= 127.f) ? 1.f : 0.f;
            float vx1 = (x0f >= -1.f && x0f <= 126.f) ? 1.f : 0.f;
            float w00 = (1.f-wy)*(1.f-wx)*vy0*vx0, w01 = (1.f-wy)*wx*vy0*vx1;
            float w10 = wy*(1.f-wx)*vy1*vx0,       w11 = wy*wx*vy1*vx1;
            int iy0 = min(max((int)y0f,     0), 127), iy1 = min(max((int)y0f + 1, 0), 127);
            int ix0 = min(max((int)x0f,     0), 127), ix1 = min(max((int)x0f + 1, 0), 127);
            const unsigned short* base = xb + (size_t)oct*8;
            uint4 u00 = *(const uint4*)(base + (size_t)(iy0*Wd + ix0)*Cd);
            uint4 u01 = *(const uint4*)(base + (size_t)(iy0*Wd + ix1)*Cd);
            uint4 u10 = *(const uint4*)(base + (size_t)(iy1*Wd + ix0)*Cd);
            uint4 u11 = *(const uint4*)(base + (size_t)(iy1*Wd + ix1)*Cd);

            unsigned a00[4] = {u00.x,u00.y,u00.z,u00.w};
            unsigned a01[4] = {u01.x,u01.y,u01.z,u01.w};
            unsigned a10[4] = {u10.x,u10.y,u10.z,u10.w};
            unsigned a11[4] = {u11.x,u11.y,u11.z,u11.w};
            f32x2 w00v = {w00, w00}, w01v = {w01, w01};
            f32x2 w10v = {w10, w10}, w11v = {w11, w11};
            unsigned pk[4];
            #pragma unroll
            for (int e = 0; e < 4; ++e) {
                f32x2 rr = bf2(a00[e])*w00v + bf2(a01[e])*w01v
                         + bf2(a10[e])*w10v + bf2(a11[e])*w11v;
                pk[e] = cvtpk(rr.x, rr.y);
            }
            int ks = 2*t + par;
            lds_b[(ks*2 + nt)*64 + slotA] = make_uint4(pk[0], pk[1], pk[2], pk[3]);
        }
    }
    __syncthreads();

    // ---- Phase B: 8 waves; wave = (cg = w&3, half = w>>2); 16co x 16px ----
    {
        int w = tid >> 6, l = tid & 63;
        int cg = w & 3, half = w >> 2;
        int pcB = l & 15, qB = l >> 4;
        int physl = (pcB ^ (qB << 1)) + (qB << 4);
        const short* wrow = g_wbf + (size_t)(cg*16 + pcB)*576 + qB*8;

        f32x4 acc = {0.f, 0.f, 0.f, 0.f};
        for (int ks = 0; ks < 18; ++ks) {
            short8 av = *(const short8*)(wrow + ks*32);
            short8 bv = *(const short8*)&lds_b[(ks*2 + half)*64 + physl];
            acc = __builtin_amdgcn_mfma_f32_16x16x32_bf16(av, bv, acc, 0, 0, 0);
        }
        #pragma unroll
        for (int rr = 0; rr < 4; ++rr) {
            int co = cg*16 + qB*4 + rr;
            out[((size_t)(b*COd + co)*Hd + i)*Wd + j0 + half*16 + pcB] = acc[rr] + bias[co];
        }
    }
}

extern "C" void kernel_launch(void* const* d_in, const int* in_sizes, int n_in,
                              void* d_out, int out_size, void* d_ws, size_t ws_size,
                              hipStream_t stream) {
    const float* x      = (const float*)d_in[0];
    const float* w_off  = (const float*)d_in[1];
    const float* b_off  = (const float*)d_in[2];
    const float* weight = (const float*)d_in[3];
    const float* bias   = (const float*)d_in[4];
    float* out = (float*)d_out;

    hipLaunchKernelGGL(k_prep,   dim3(692),  dim3(256), 0, stream, x, weight, w_off);
    hipLaunchKernelGGL(k_offs,   dim3(1024), dim3(256), 0, stream, b_off);
    hipLaunchKernelGGL(k_deform, dim3(2048), dim3(512), 0, stream, bias, out);
}

// Round 11
// 59.676 us; speedup vs baseline: 1.3199x; 1.3199x over previous
//
#include <hip/hip_runtime.h>

#define Hd 128
#define Wd 128
#define Cd 64
#define COd 64
#define Bd 4
#define HWd (Hd*Wd)

typedef __attribute__((ext_vector_type(8))) _Float16 half8;
typedef __attribute__((ext_vector_type(2))) _Float16 h2;
typedef __attribute__((ext_vector_type(4))) float    f32x4;

// Static device scratch (fp16 everywhere).
__device__ __align__(16) _Float16 g_wh[COd*576];                 // W[co][k], k=t*64+c
__device__ __align__(16) _Float16 g_woffh[16*576];               // w_off padded to 16 rows
__device__ float4 g_offs[Bd*HWd];                                // (off0, off1, s1, s2)
__device__ __align__(16) unsigned short g_xt[(size_t)Bd*HWd*Cd]; // fp16 NHWC x

static __device__ __forceinline__ unsigned cvtpkh(float lo, float hi) {
    unsigned r;
    asm("v_cvt_pkrtz_f16_f32 %0, %1, %2" : "=v"(r) : "v"(lo), "v"(hi));
    return r;
}
static __device__ __forceinline__ h2 ash2(unsigned u) {
    union { unsigned u; h2 h; } x; x.u = u; return x.h;
}
static __device__ __forceinline__ unsigned ash2u(h2 h) {
    union { h2 h; unsigned u; } x; x.h = h; return x.u;
}

// Prep: [0,512) NHWC fp16 ; [512,656) W->fp16 ; [656,692) w_off padded fp16.
__global__ __launch_bounds__(256) void k_prep(const float* __restrict__ x,
                                              const float* __restrict__ weight,
                                              const float* __restrict__ w_off) {
    int bid = blockIdx.x;
    if (bid < 512) {
        int b = bid >> 7, y = bid & 127;
        int px = threadIdx.x & 127;
        int h  = threadIdx.x >> 7;
        const float* xb = x + (size_t)b*Cd*HWd + y*Wd + px;
        unsigned short* ob = g_xt + ((size_t)(b*HWd) + y*Wd + px)*Cd + h*32;
        #pragma unroll
        for (int oct = 0; oct < 4; ++oct) {
            unsigned pk[4];
            #pragma unroll
            for (int e = 0; e < 4; ++e) {
                float v0 = xb[(size_t)(h*32 + oct*8 + 2*e    )*HWd];
                float v1 = xb[(size_t)(h*32 + oct*8 + 2*e + 1)*HWd];
                pk[e] = cvtpkh(v0, v1);
            }
            *(uint4*)(ob + oct*8) = make_uint4(pk[0], pk[1], pk[2], pk[3]);
        }
    } else if (bid < 656) {
        int g = (bid - 512)*256 + threadIdx.x;     // 64*576
        if (g < COd*576) {
            int co = g / 576, k = g % 576;
            int t = k >> 6, c = k & 63;            // k = t*64 + c
            g_wh[g] = (_Float16)weight[(co*Cd + c)*9 + t];
        }
    } else {
        int g = (bid - 656)*256 + threadIdx.x;     // 16*576 = 9216
        if (g < 16*576) {
            int row = g / 576, k = g % 576;
            int t = k >> 6, c = k & 63;
            g_woffh[g] = (row < 4) ? (_Float16)w_off[(row*Cd + c)*9 + t] : (_Float16)0.f;
        }
    }
}

// Offsets conv as MFMA mini-GEMM (r9 form, fp16): 1024 blocks x 64 px.
__global__ __launch_bounds__(256) void k_offs(const float* __restrict__ b_off) {
    int orig = blockIdx.x;               // 1024, XCD-banded
    int xcd = orig & 7, slot = orig >> 3;          // 0..127
    int g = xcd*2 + (slot >> 6);
    int s = slot & 63;
    int b  = g >> 2;
    int i  = (g & 3)*32 + (s >> 1);
    int j0 = (s & 1) << 6;

    int w  = threadIdx.x >> 6;
    int l  = threadIdx.x & 63;
    int pc = l & 15, q = l >> 4;
    int j  = j0 + w*16 + pc;

    const unsigned short* xb = g_xt + (size_t)b*HWd*Cd;
    const _Float16* arow = g_woffh + pc*576 + q*8;

    f32x4 acc = {0.f, 0.f, 0.f, 0.f};
    #pragma unroll
    for (int t = 0; t < 9; ++t) {
        int yy = i + t/3 - 1, xx = j + t%3 - 1;
        bool ok = (yy >= 0) & (yy <= 127) & (xx >= 0) & (xx <= 127);
        const unsigned short* p = xb + (size_t)(yy*Wd + xx)*Cd + q*8;
        uint4 u0 = ok ? *(const uint4*)p        : make_uint4(0,0,0,0);
        uint4 u1 = ok ? *(const uint4*)(p + 32) : make_uint4(0,0,0,0);
        half8 b0 = *(half8*)&u0;
        half8 b1 = *(half8*)&u1;
        half8 a0 = *(const half8*)(arow + (2*t    )*32);
        half8 a1 = *(const half8*)(arow + (2*t + 1)*32);
        acc = __builtin_amdgcn_mfma_f32_16x16x32_f16(a0, b0, acc, 0, 0, 0);
        acc = __builtin_amdgcn_mfma_f32_16x16x32_f16(a1, b1, acc, 0, 0, 0);
    }
    if (q == 0) {   // lanes 0..15: D rows 0..3 for pixel pc
        float o0 = acc[0] + b_off[0];
        float o1 = acc[1] + b_off[1];
        float o2 = fmaxf(acc[2] + b_off[2], 0.f) + 1.f;
        float o3 = fmaxf(acc[3] + b_off[3], 0.f) + 1.f;
        g_offs[(b*Hd + i)*Wd + j] = make_float4(o0, o1, o2, o3);
    }
}

#define GATHER(T, U00, U01, U10, U11, H00, H01, H10, H11)                         \
    {                                                                             \
        float ys = (float)(i - 1) + (float)((T)/3 - 1)*s1v + off0;                \
        float xs = (float)(jA - 1) + (float)((T)%3 - 1)*s2v + off1;               \
        float y0f = floorf(ys), x0f = floorf(xs);                                 \
        float wy = ys - y0f, wx = xs - x0f;                                       \
        float vy0 = (y0f >=  0.f && y0f <= 127.f) ? 1.f : 0.f;                    \
        float vy1 = (y0f >= -1.f && y0f <= 126.f) ? 1.f : 0.f;                    \
        float vx0 = (x0f >=  0.f && x0f <= 127.f) ? 1.f : 0.f;                    \
        float vx1 = (x0f >= -1.f && x0f <= 126.f) ? 1.f : 0.f;                    \
        float w00 = (1.f-wy)*(1.f-wx)*vy0*vx0, w01 = (1.f-wy)*wx*vy0*vx1;         \
        float w10 = wy*(1.f-wx)*vy1*vx0,       w11 = wy*wx*vy1*vx1;               \
        H00 = ash2(cvtpkh(w00, w00)); H01 = ash2(cvtpkh(w01, w01));               \
        H10 = ash2(cvtpkh(w10, w10)); H11 = ash2(cvtpkh(w11, w11));               \
        int iy0 = min(max((int)y0f,     0), 127), iy1 = min(max((int)y0f+1,0),127);\
        int ix0 = min(max((int)x0f,     0), 127), ix1 = min(max((int)x0f+1,0),127);\
        U00 = *(const uint4*)(xb + (size_t)(iy0*Wd + ix0)*Cd + oct*8);            \
        U01 = *(const uint4*)(xb + (size_t)(iy0*Wd + ix1)*Cd + oct*8);            \
        U10 = *(const uint4*)(xb + (size_t)(iy1*Wd + ix0)*Cd + oct*8);            \
        U11 = *(const uint4*)(xb + (size_t)(iy1*Wd + ix1)*Cd + oct*8);            \
    }

#define PACK_STORE(BUF, U00, U01, U10, U11, H00, H01, H10, H11)                   \
    {                                                                             \
        unsigned a00[4] = {U00.x,U00.y,U00.z,U00.w};                              \
        unsigned a01[4] = {U01.x,U01.y,U01.z,U01.w};                              \
        unsigned a10[4] = {U10.x,U10.y,U10.z,U10.w};                              \
        unsigned a11[4] = {U11.x,U11.y,U11.z,U11.w};                              \
        unsigned pk[4];                                                           \
        _Pragma("unroll")                                                         \
        for (int e = 0; e < 4; ++e) {                                             \
            h2 r = ash2(a00[e])*H00 + ash2(a01[e])*H01                            \
                 + ash2(a10[e])*H10 + ash2(a11[e])*H11;                           \
            pk[e] = ash2u(r);                                                     \
        }                                                                         \
        lds_b[(((BUF)*2 + par)*2 + nt)*64 + slotA] = make_uint4(pk[0],pk[1],pk[2],pk[3]); \
    }

// Pipelined deform (r8 structure, fp16): 2048 blocks x 32 px; dbuf 8KB; 1 barrier/tap.
__global__ __launch_bounds__(256) void k_deform(const float* __restrict__ bias,
                                                float* __restrict__ out) {
    __shared__ uint4 lds_b[2*2*2*64];    // [buf][parity][half][slot] = 8 KB
    int orig = blockIdx.x;               // 2048, same banding as k_offs
    int xcd = orig & 7, slotB = orig >> 3;
    int g = xcd*2 + (slotB >> 7);
    int s = slotB & 127;
    int b = g >> 2;
    int i = (g & 3)*32 + (s >> 2);
    int j0 = (s & 3) << 5;

    int w = threadIdx.x >> 6, l = threadIdx.x & 63;
    // Phase-A identity (gather/pack)
    int oct = l & 7, px8 = l >> 3;
    int pxl = w*8 + px8;                 // 0..31
    int jA  = j0 + pxl;
    int nt = pxl >> 4, pcA = pxl & 15, qA = oct & 3, par = oct >> 2;
    int slotA = (pcA ^ (qA << 1)) + (qA << 4);
    // Phase-B identity (mfma/store)
    int pcB = l & 15, qB = l >> 4;
    int physl = (pcB ^ (qB << 1)) + (qB << 4);
    const _Float16* wrow = g_wh + (size_t)(w*16 + pcB)*576 + qB*8;

    const unsigned short* xb = g_xt + (size_t)b*HWd*Cd;
    float4 o4 = g_offs[(b*Hd + i)*Wd + jA];
    float off0 = o4.x, off1 = o4.y, s1v = o4.z, s2v = o4.w;

    f32x4 acc0 = {0.f,0.f,0.f,0.f};
    f32x4 acc1 = {0.f,0.f,0.f,0.f};

    uint4 gc00, gc01, gc10, gc11, gn00, gn01, gn10, gn11;
    h2 hc00, hc01, hc10, hc11, hn00, hn01, hn10, hn11;
    half8 ac0, ac1, an0, an1;

    GATHER(0, gc00, gc01, gc10, gc11, hc00, hc01, hc10, hc11);
    ac0 = *(const half8*)(wrow + 0*32);
    ac1 = *(const half8*)(wrow + 1*32);

    #pragma unroll
    for (int t = 0; t < 9; ++t) {
        if (t < 8) {
            GATHER(t+1, gn00, gn01, gn10, gn11, hn00, hn01, hn10, hn11);
            an0 = *(const half8*)(wrow + (2*t + 2)*32);
            an1 = *(const half8*)(wrow + (2*t + 3)*32);
        }
        PACK_STORE(t & 1, gc00, gc01, gc10, gc11, hc00, hc01, hc10, hc11);
        __syncthreads();
        {
            half8 b00 = *(const half8*)&lds_b[(((t&1)*2 + 0)*2 + 0)*64 + physl];
            half8 b01 = *(const half8*)&lds_b[(((t&1)*2 + 0)*2 + 1)*64 + physl];
            half8 b10 = *(const half8*)&lds_b[(((t&1)*2 + 1)*2 + 0)*64 + physl];
            half8 b11 = *(const half8*)&lds_b[(((t&1)*2 + 1)*2 + 1)*64 + physl];
            acc0 = __builtin_amdgcn_mfma_f32_16x16x32_f16(ac0, b00, acc0, 0, 0, 0);
            acc1 = __builtin_amdgcn_mfma_f32_16x16x32_f16(ac0, b01, acc1, 0, 0, 0);
            acc0 = __builtin_amdgcn_mfma_f32_16x16x32_f16(ac1, b10, acc0, 0, 0, 0);
            acc1 = __builtin_amdgcn_mfma_f32_16x16x32_f16(ac1, b11, acc1, 0, 0, 0);
        }
        if (t < 8) {
            gc00 = gn00; gc01 = gn01; gc10 = gn10; gc11 = gn11;
            hc00 = hn00; hc01 = hn01; hc10 = hn10; hc11 = hn11;
            ac0 = an0; ac1 = an1;
        }
    }

    // store: D col = pcB (=px), row = qB*4 + rr -> co = w*16 + qB*4 + rr
    #pragma unroll
    for (int rr = 0; rr < 4; ++rr) {
        int co = w*16 + qB*4 + rr;
        float bco = bias[co];
        size_t base = ((size_t)(b*COd + co)*Hd + i)*Wd + j0;
        out[base + pcB]      = acc0[rr] + bco;
        out[base + 16 + pcB] = acc1[rr] + bco;
    }
}

extern "C" void kernel_launch(void* const* d_in, const int* in_sizes, int n_in,
                              void* d_out, int out_size, void* d_ws, size_t ws_size,
                              hipStream_t stream) {
    const float* x      = (const float*)d_in[0];
    const float* w_off  = (const float*)d_in[1];
    const float* b_off  = (const float*)d_in[2];
    const float* weight = (const float*)d_in[3];
    const float* bias   = (const float*)d_in[4];
    float* out = (float*)d_out;

    hipLaunchKernelGGL(k_prep,   dim3(692),  dim3(256), 0, stream, x, weight, w_off);
    hipLaunchKernelGGL(k_offs,   dim3(1024), dim3(256), 0, stream, b_off);
    hipLaunchKernelGGL(k_deform, dim3(2048), dim3(256), 0, stream, bias, out);
}